// Round 5
// baseline (194.637 us; speedup 1.0000x reference)
//
#include <hip/hip_runtime.h>
#include <hip/hip_bf16.h>
#include <math.h>

// Problem constants: N=10000, E=160000, D=128, H=4, C=128, HC=512
#define D_DIM 128
#define HC_DIM 512
#define CAP 128  // per-node edge bucket capacity (deg ~ Poisson(16); P(deg>=128)<1e-60)
#define REP 4    // colsum/colsq replica slots (per-address atomic depth 2500/REP=625)

typedef __attribute__((ext_vector_type(8))) short bf16x8;
typedef __attribute__((ext_vector_type(4))) float f32x4;
typedef __attribute__((ext_vector_type(2))) float f32x2;

static __device__ __forceinline__ unsigned short f2bf(float f) {
  unsigned u = __float_as_uint(f);
  unsigned r = (u + 0x7fffu + ((u >> 16) & 1u)) >> 16;  // RNE
  return (unsigned short)r;
}
static __device__ __forceinline__ float bflo(unsigned u) {
  return __uint_as_float(u << 16);
}
static __device__ __forceinline__ float bfhi(unsigned u) {
  return __uint_as_float(u & 0xffff0000u);
}

// ---------------------------------------------------------------------------
// prep: cast x -> bf16; build Wt [1664][128] bf16 (coalesced source reads);
// bcat[1664]; zero counter region (cnt|colsum|colsq).
// ---------------------------------------------------------------------------
__global__ void prep_kernel(const float* __restrict__ x,
                            const float* __restrict__ Wq, const float* __restrict__ Wk,
                            const float* __restrict__ Wv, const float* __restrict__ Wskip,
                            const float* __restrict__ bq, const float* __restrict__ bk,
                            const float* __restrict__ bv, const float* __restrict__ bskip,
                            unsigned short* __restrict__ xb,
                            unsigned short* __restrict__ wcat,
                            float* __restrict__ bcat,
                            int* __restrict__ zbase, int zwords, int N) {
  int t = blockIdx.x * 256 + threadIdx.x;
  int X4 = N * 32;  // x float4 count
  if (t < X4) {
    float4 f = *(const float4*)&x[t * 4];
    ushort4 o;
    o.x = f2bf(f.x); o.y = f2bf(f.y); o.z = f2bf(f.z); o.w = f2bf(f.w);
    *(ushort4*)&xb[t * 4] = o;
  } else if (t < X4 + 1664 * 128) {
    int widx = t - X4;
    if (widx < 3 * 65536) {
      int segi = widx >> 16;       // 0=q 1=k 2=v
      int r = widx & 65535;
      int kk = r >> 9;             // 0..127
      int m = r & 511;             // consecutive -> coalesced source read
      const float* W = (segi == 0) ? Wq : (segi == 1) ? Wk : Wv;
      wcat[(size_t)(segi * 512 + m) * 128 + kk] = f2bf(W[kk * 512 + m]);
    } else {
      int r = widx - 3 * 65536;    // < 16384
      int kk = r >> 7;
      int m = r & 127;
      wcat[(size_t)(1536 + m) * 128 + kk] = f2bf(Wskip[kk * 128 + m]);
    }
  } else if (t < X4 + 1664 * 128 + 1664) {
    int b = t - X4 - 1664 * 128;
    bcat[b] = (b < 512) ? bq[b] : (b < 1024) ? bk[b - 512]
            : (b < 1536) ? bv[b - 1024] : bskip[b - 1536];
  } else if (t < X4 + 1664 * 128 + 1664 + zwords) {
    zbase[t - X4 - 1664 * 128 - 1664] = 0;
  }
}

// ---------------------------------------------------------------------------
// LDS-free MFMA GEMM + slotted edge scatter (no hist/scan needed).
// [N x 1664] = Xb[N x 128] @ Wt[1664 x 128]^T + bcat.
// cols 0-511 -> q bf16; 512-1023 -> k fp8; 1024-1535 -> v fp8;
// 1536-1663 -> skip fp32.
// ---------------------------------------------------------------------------
__global__ __launch_bounds__(256) void gemm_mfma_kernel(
    const unsigned short* __restrict__ Xb, const unsigned short* __restrict__ Wt,
    const float* __restrict__ bcat, unsigned short* __restrict__ qb,
    unsigned char* __restrict__ k8, unsigned char* __restrict__ v8,
    float* __restrict__ skip,
    const int* __restrict__ src, const int* __restrict__ dst,
    int* __restrict__ cnt, int* __restrict__ bsrc, int N, int E) {
  const int tid = threadIdx.x;
  // --- slotted scatter slice (no barriers anywhere in this kernel) ---
  {
    int nblk = gridDim.x * gridDim.y;
    int lb = blockIdx.y * gridDim.x + blockIdx.x;
    int per = (E + nblk - 1) / nblk;
    int e0 = lb * per;
    int e1 = min(e0 + per, E);
    for (int e = e0 + tid; e < e1; e += 256) {
      int d = dst[e];
      int p = atomicAdd(&cnt[d], 1);
      if (p < CAP) bsrc[d * CAP + p] = src[e];
    }
  }
  // --- GEMM ---
  const int wave = tid >> 6, lane = tid & 63;
  const int l16 = lane & 15, quad = lane >> 4;
  const int row0 = (blockIdx.x * 4 + wave) * 64;  // wave's 64-row slab
  const int col0 = blockIdx.y * 64;               // wave's 64-col slab

  const unsigned short* xrow[4];
#pragma unroll
  for (int i = 0; i < 4; ++i) {
    int r = row0 + i * 16 + l16;
    if (r >= N) r = N - 1;  // clamp; stores masked later
    xrow[i] = Xb + (size_t)r * 128;
  }
  const unsigned short* wrow[4];
  float bias[4];
#pragma unroll
  for (int j = 0; j < 4; ++j) {
    int c = col0 + j * 16 + l16;
    wrow[j] = Wt + (size_t)c * 128;
    bias[j] = bcat[c];
  }

  f32x4 acc[4][4] = {};
#pragma unroll
  for (int kk = 0; kk < 4; ++kk) {
    int k0 = kk * 32 + quad * 8;
    bf16x8 a[4], b[4];
#pragma unroll
    for (int i = 0; i < 4; ++i) a[i] = *(const bf16x8*)(xrow[i] + k0);
#pragma unroll
    for (int j = 0; j < 4; ++j) b[j] = *(const bf16x8*)(wrow[j] + k0);
#pragma unroll
    for (int i = 0; i < 4; ++i)
#pragma unroll
      for (int j = 0; j < 4; ++j)
        acc[i][j] = __builtin_amdgcn_mfma_f32_16x16x32_bf16(a[i], b[j], acc[i][j], 0, 0, 0);
  }

  // wave-uniform output kind: 0=q bf16, 1=k fp8, 2=v fp8, 3=skip fp32
  const int kind = (col0 < 512) ? 0 : (col0 < 1024) ? 1 : (col0 < 1536) ? 2 : 3;
#pragma unroll
  for (int i = 0; i < 4; ++i) {
#pragma unroll
    for (int reg = 0; reg < 4; ++reg) {
      int r = row0 + i * 16 + quad * 4 + reg;
      if (r < N) {
#pragma unroll
        for (int j = 0; j < 4; ++j) {
          int cidx = col0 + j * 16 + l16;
          float val = acc[i][j][reg] + bias[j];
          if (kind == 0) {
            qb[(size_t)r * 512 + cidx] = f2bf(val);
          } else if (kind == 1) {
            int pk = __builtin_amdgcn_cvt_pk_fp8_f32(val, val, 0, false);
            k8[(size_t)r * 512 + cidx - 512] = (unsigned char)pk;
          } else if (kind == 2) {
            int pk = __builtin_amdgcn_cvt_pk_fp8_f32(val, val, 0, false);
            v8[(size_t)r * 512 + cidx - 1024] = (unsigned char)pk;
          } else {
            skip[(size_t)r * 128 + cidx - 1536] = val;
          }
        }
      }
    }
  }
}

// decode one fp8 word (4 dims) into the dot accumulator
#define DOT8(u, r0, acc) { \
  f32x2 l_ = __builtin_amdgcn_cvt_pk_f32_fp8((u), false); \
  f32x2 h_ = __builtin_amdgcn_cvt_pk_f32_fp8((u), true); \
  acc = fmaf(qf[r0], l_.x, acc); acc = fmaf(qf[(r0) + 1], l_.y, acc); \
  acc = fmaf(qf[(r0) + 2], h_.x, acc); acc = fmaf(qf[(r0) + 3], h_.y, acc); }

// decode one fp8 v word (4 dims) into o accumulators with weight wgt
#define VACC(u, r0) { \
  f32x2 l_ = __builtin_amdgcn_cvt_pk_f32_fp8((u), false); \
  f32x2 h_ = __builtin_amdgcn_cvt_pk_f32_fp8((u), true); \
  o[r0] = fmaf(wgt, l_.x, o[r0]); o[(r0) + 1] = fmaf(wgt, l_.y, o[(r0) + 1]); \
  o[(r0) + 2] = fmaf(wgt, h_.x, o[(r0) + 2]); o[(r0) + 3] = fmaf(wgt, h_.y, o[(r0) + 3]); }

// ---------------------------------------------------------------------------
// Fused attention + combine, 32B/LANE GATHER LAYOUT.
// Rounds 1-4 showed dur invariant to structure (x3), parallelism (x4) and
// bytes (-33%) but NEVER varied VMEM instruction count (8 per 4-edge iter).
// This version: each 16-lane group covers one edge's FULL 512B k-row and
// 512B v-row at 32B/lane (lane j -> head j>>2, dims (j&3)*32..+32), i.e.
// 2 uint4 loads for k + 2 for v = 4 wave-instrs per 4-edge iteration
// (halved) at identical bytes/segments -> clean test of the
// gather-instruction-rate hypothesis.
// Dot: 32 fma/lane (4 partials) then shfl_xor(1,2) over the head-quarter.
// Head-mean: post-normalize shfl_xor(4,8). Group-sum: shfl_xor(16,32).
// Block = 4 nodes (wave = node); edge list in LDS; depth-1 prefetch;
// beta gate + out2 + column moments in-block (REP=4 replica atomics).
// ---------------------------------------------------------------------------
__global__ __launch_bounds__(256) void attn_combine_kernel(
    const unsigned short* __restrict__ qb, const unsigned char* __restrict__ k8,
    const unsigned char* __restrict__ v8, const int* __restrict__ cnt,
    const int* __restrict__ bsrc, const float* __restrict__ skip,
    const float* __restrict__ Wbeta, float* __restrict__ out2,
    float* __restrict__ colsum, float* __restrict__ colsq, int N) {
  __shared__ int eL[4][CAP];        // per-wave edge list (wave-local, no sync needed)
  __shared__ float redS[4][128];
  __shared__ float redQ[4][128];
  int tid = threadIdx.x;
  int w = tid >> 6, lane = tid & 63;
  int node = blockIdx.x * 4 + w;
  bool nv = node < N;
  int nc = nv ? node : (N - 1);     // clamped for addressing; contributions masked
  int g = lane >> 4, j = lane & 15;

  int count = nv ? min(cnt[nc], CAP) : 0;
  const int* bp = bsrc + (size_t)nc * CAP;
  for (int i = lane; i < count; i += 64) eL[w][i] = bp[i];

  const float qscale = 0.08838834764831845f * 1.4426950408889634f;  // /sqrt(128)*log2e
  // stage q: this lane's head (j>>2), dims (j&3)*32..+32, scaled f32
  float qf[32];
  {
    const unsigned short* qrow = qb + (size_t)nc * 512 + (j >> 2) * 128 + (j & 3) * 32;
    int4 q0 = *(const int4*)(qrow);
    int4 q1 = *(const int4*)(qrow + 8);
    int4 q2 = *(const int4*)(qrow + 16);
    int4 q3 = *(const int4*)(qrow + 24);
    qf[0] = bflo(q0.x) * qscale;  qf[1] = bfhi(q0.x) * qscale;
    qf[2] = bflo(q0.y) * qscale;  qf[3] = bfhi(q0.y) * qscale;
    qf[4] = bflo(q0.z) * qscale;  qf[5] = bfhi(q0.z) * qscale;
    qf[6] = bflo(q0.w) * qscale;  qf[7] = bfhi(q0.w) * qscale;
    qf[8] = bflo(q1.x) * qscale;  qf[9] = bfhi(q1.x) * qscale;
    qf[10] = bflo(q1.y) * qscale; qf[11] = bfhi(q1.y) * qscale;
    qf[12] = bflo(q1.z) * qscale; qf[13] = bfhi(q1.z) * qscale;
    qf[14] = bflo(q1.w) * qscale; qf[15] = bfhi(q1.w) * qscale;
    qf[16] = bflo(q2.x) * qscale; qf[17] = bfhi(q2.x) * qscale;
    qf[18] = bflo(q2.y) * qscale; qf[19] = bfhi(q2.y) * qscale;
    qf[20] = bflo(q2.z) * qscale; qf[21] = bfhi(q2.z) * qscale;
    qf[22] = bflo(q2.w) * qscale; qf[23] = bfhi(q2.w) * qscale;
    qf[24] = bflo(q3.x) * qscale; qf[25] = bfhi(q3.x) * qscale;
    qf[26] = bflo(q3.y) * qscale; qf[27] = bfhi(q3.y) * qscale;
    qf[28] = bflo(q3.z) * qscale; qf[29] = bfhi(q3.z) * qscale;
    qf[30] = bflo(q3.w) * qscale; qf[31] = bfhi(q3.w) * qscale;
  }

  float o[32];
#pragma unroll
  for (int r = 0; r < 32; ++r) o[r] = 0.f;
  float lsum = 0.f;   // this lane's head's softmax denom partial (group-local)

  if (count > 0) {
    // prologue prefetch: group g's edge; lane covers its 32B of k and v rows
    int e = eL[w][(g < count) ? g : 0];
    const unsigned char* kp = k8 + (size_t)e * 512 + j * 32;
    const unsigned char* vp = v8 + (size_t)e * 512 + j * 32;
    uint4 ka = *(const uint4*)kp;
    uint4 kb = *(const uint4*)(kp + 16);
    uint4 va = *(const uint4*)vp;
    uint4 vb = *(const uint4*)(vp + 16);
    for (int idx = 0; idx < count; idx += 4) {
      int rem = count - idx;
      int nrem = rem - 4;
      int en = (nrem > 0) ? eL[w][idx + 4 + ((g < nrem) ? g : 0)] : e;
      const unsigned char* kpn = k8 + (size_t)en * 512 + j * 32;
      const unsigned char* vpn = v8 + (size_t)en * 512 + j * 32;
      uint4 kan = *(const uint4*)kpn;
      uint4 kbn = *(const uint4*)(kpn + 16);
      uint4 van = *(const uint4*)vpn;
      uint4 vbn = *(const uint4*)(vpn + 16);
      // dot over this lane's 32 dims (4 ILP partials)
      float p0 = 0.f, p1 = 0.f, p2 = 0.f, p3 = 0.f;
      DOT8(ka.x, 0, p0);  DOT8(ka.y, 4, p1);  DOT8(ka.z, 8, p2);  DOT8(ka.w, 12, p3);
      DOT8(kb.x, 16, p0); DOT8(kb.y, 20, p1); DOT8(kb.z, 24, p2); DOT8(kb.w, 28, p3);
      float p = (p0 + p1) + (p2 + p3);
      // reduce over the head-quarter (4 lanes, dim-blocks 0..3)
      p += __shfl_xor(p, 1);
      p += __shfl_xor(p, 2);
      float a = (g < rem) ? p : -1e30f;
      float wgt = exp2f(a);  // exp2(-1e30) = 0 for inactive slots
      lsum += wgt;
      VACC(va.x, 0);  VACC(va.y, 4);  VACC(va.z, 8);  VACC(va.w, 12);
      VACC(vb.x, 16); VACC(vb.y, 20); VACC(vb.z, 24); VACC(vb.w, 28);
      // rotate
      ka = kan; kb = kbn; va = van; vb = vbn; e = en;
    }
  }

  // cross-group (edge-slot) sums: per-head totals on every lane
#pragma unroll
  for (int r = 0; r < 32; ++r) {
    o[r] += __shfl_xor(o[r], 16);
    o[r] += __shfl_xor(o[r], 32);
  }
  lsum += __shfl_xor(lsum, 16);
  lsum += __shfl_xor(lsum, 32);
  float inv = 0.25f / (lsum + 1e-16f);   // fold head-mean 1/4 into normalization
#pragma unroll
  for (int r = 0; r < 32; ++r) o[r] *= inv;
  // head-sum across the 4 quarters -> am for dim (lane&3)*32 + r
#pragma unroll
  for (int r = 0; r < 32; ++r) {
    o[r] += __shfl_xor(o[r], 4);
    o[r] += __shfl_xor(o[r], 8);
  }

  // --- beta gate: lane covers dims d0..d0+31, d0=(lane&3)*32 ---
  int d0 = (lane & 3) * 32;
  const float* sp = skip + (size_t)nc * 128 + d0;
  float s[32];
  float pb = 0.f;
#pragma unroll
  for (int q4 = 0; q4 < 8; ++q4) {
    float4 sv = *(const float4*)(sp + q4 * 4);
    float4 wa = *(const float4*)(Wbeta + d0 + q4 * 4);
    float4 wb = *(const float4*)(Wbeta + 128 + d0 + q4 * 4);
    float4 wc = *(const float4*)(Wbeta + 256 + d0 + q4 * 4);
    s[q4 * 4 + 0] = sv.x; s[q4 * 4 + 1] = sv.y;
    s[q4 * 4 + 2] = sv.z; s[q4 * 4 + 3] = sv.w;
    pb += o[q4 * 4 + 0] * wa.x + sv.x * wb.x + (o[q4 * 4 + 0] - sv.x) * wc.x
        + o[q4 * 4 + 1] * wa.y + sv.y * wb.y + (o[q4 * 4 + 1] - sv.y) * wc.y
        + o[q4 * 4 + 2] * wa.z + sv.z * wb.z + (o[q4 * 4 + 2] - sv.z) * wc.z
        + o[q4 * 4 + 3] * wa.w + sv.w * wb.w + (o[q4 * 4 + 3] - sv.w) * wc.w;
  }
  // full 384-dot: sum over the 4 dim-blocks within the quarter
  pb += __shfl_xor(pb, 1);
  pb += __shfl_xor(pb, 2);
  float beta = 1.f / (1.f + __expf(-pb));
  float ob = 1.f - beta;
  float vm = nv ? 1.f : 0.f;
  float oc[32];
#pragma unroll
  for (int r = 0; r < 32; ++r) oc[r] = (beta * s[r] + ob * o[r]) * vm;

  // lanes 0..3 (g=0, head-quarter 0) hold dim-blocks 0..3 -> write 32 dims each
  if (lane < 4) {
    size_t obase = (size_t)node * 128 + lane * 32;
#pragma unroll
    for (int q4 = 0; q4 < 8; ++q4) {
      float4 vs;
      vs.x = oc[q4 * 4 + 0]; vs.y = oc[q4 * 4 + 1];
      vs.z = oc[q4 * 4 + 2]; vs.w = oc[q4 * 4 + 3];
      if (nv) *(float4*)&out2[obase + q4 * 4] = vs;
      *(float4*)&redS[w][lane * 32 + q4 * 4] = vs;
      float4 vq;
      vq.x = vs.x * vs.x; vq.y = vs.y * vs.y;
      vq.z = vs.z * vs.z; vq.w = vs.w * vs.w;
      *(float4*)&redQ[w][lane * 32 + q4 * 4] = vq;
    }
  }
  __syncthreads();
  if (w == 0) {
    int c = lane * 2;
    float s0 = redS[0][c] + redS[1][c] + redS[2][c] + redS[3][c];
    float s1 = redS[0][c + 1] + redS[1][c + 1] + redS[2][c + 1] + redS[3][c + 1];
    float q0 = redQ[0][c] + redQ[1][c] + redQ[2][c] + redQ[3][c];
    float q1 = redQ[0][c + 1] + redQ[1][c + 1] + redQ[2][c + 1] + redQ[3][c + 1];
    int slot = (blockIdx.x & (REP - 1)) * 128;
    atomicAdd(&colsum[slot + c], s0);
    atomicAdd(&colsum[slot + c + 1], s1);
    atomicAdd(&colsq[slot + c], q0);
    atomicAdd(&colsq[slot + c + 1], q1);
  }
}

// ---------------------------------------------------------------------------
// finalize: sum REP replica column stats + groupnorm + exact GELU + residual
// ---------------------------------------------------------------------------
__global__ void final_kernel(const float* __restrict__ out2,
                             const float* __restrict__ colsum,
                             const float* __restrict__ colsq,
                             const float* __restrict__ gnw,
                             const float* __restrict__ gnb,
                             const float* __restrict__ gnms,
                             const float* __restrict__ x,
                             float* __restrict__ y, int total2, float invN) {
  int i = blockIdx.x * 256 + threadIdx.x;
  if (i < total2) {
    int c = (i & 63) * 2;
    float2 cs; cs.x = 0.f; cs.y = 0.f;
    float2 cq; cq.x = 0.f; cq.y = 0.f;
#pragma unroll
    for (int s = 0; s < REP; ++s) {
      float2 t = *(const float2*)&colsum[s * 128 + c];
      float2 u = *(const float2*)&colsq[s * 128 + c];
      cs.x += t.x; cs.y += t.y;
      cq.x += u.x; cq.y += u.y;
    }
    float2 gw = *(const float2*)&gnw[c];
    float2 gb = *(const float2*)&gnb[c];
    float2 gs = *(const float2*)&gnms[c];
    float mean0 = cs.x * invN, mean1 = cs.y * invN;
    float var0 = cq.x * invN - mean0 * mean0 * gs.x * (2.f - gs.x);
    float var1 = cq.y * invN - mean1 * mean1 * gs.y * (2.f - gs.y);
    float mul0 = gw.x / sqrtf(var0 + 1e-5f);
    float mul1 = gw.y / sqrtf(var1 + 1e-5f);
    float2 o = *(const float2*)&out2[i * 2];
    float2 xx = *(const float2*)&x[i * 2];
    float t0 = (o.x - gs.x * mean0) * mul0 + gb.x;
    float t1 = (o.y - gs.y * mean1) * mul1 + gb.y;
    float g0 = 0.5f * t0 * (1.f + erff(t0 * 0.70710678118654752f));
    float g1 = 0.5f * t1 * (1.f + erff(t1 * 0.70710678118654752f));
    float2 r; r.x = g0 + xx.x; r.y = g1 + xx.y;
    *(float2*)&y[i * 2] = r;
  }
}

extern "C" void kernel_launch(void* const* d_in, const int* in_sizes, int n_in,
                              void* d_out, int out_size, void* d_ws, size_t ws_size,
                              hipStream_t stream) {
  const float* x     = (const float*)d_in[0];
  const int*   ei    = (const int*)d_in[1];
  const float* Wq    = (const float*)d_in[2];
  const float* bq    = (const float*)d_in[3];
  const float* Wk    = (const float*)d_in[4];
  const float* bk    = (const float*)d_in[5];
  const float* Wv    = (const float*)d_in[6];
  const float* bv    = (const float*)d_in[7];
  const float* Wskip = (const float*)d_in[8];
  const float* bskip = (const float*)d_in[9];
  const float* Wbeta = (const float*)d_in[10];
  const float* gnw   = (const float*)d_in[11];
  const float* gnb   = (const float*)d_in[12];
  const float* gnms  = (const float*)d_in[13];

  const int N = in_sizes[0] / D_DIM;   // 10000
  const int E = in_sizes[1] / 2;       // 160000
  const int* src = ei;
  const int* dst = ei + E;

  // workspace carve-up (alias: xb over out2 — disjoint lifetimes:
  // xb dead after gemm; out2 first written in attn_combine)
  char* p = (char*)d_ws;
  unsigned short* qb = (unsigned short*)p; p += (size_t)N * 512 * 2;      // q bf16
  unsigned char*  k8 = (unsigned char*)p;  p += (size_t)N * 512;          // k fp8
  unsigned char*  v8 = (unsigned char*)p;  p += (size_t)N * 512;          // v fp8
  float*          skip = (float*)p;        p += (size_t)N * 128 * 4;
  float*          out2 = (float*)p;        p += (size_t)N * 128 * 4;
  // contiguous zero region: cnt | colsum[REP][128] | colsq[REP][128]
  int*   cnt    = (int*)p;   p += (size_t)N * 4;
  float* colsum = (float*)p; p += REP * 128 * 4;
  float* colsq  = (float*)p; p += REP * 128 * 4;
  int zwords = N + 2 * REP * 128;
  int* bsrc   = (int*)p;   p += (size_t)N * CAP * 4;  // slotted buckets
  unsigned short* wcat = (unsigned short*)p; p += (size_t)1664 * 128 * 2;
  float* bcat = (float*)p; p += 1664 * 4;
  unsigned short* xb = (unsigned short*)out2;  // alias

  // 1) prep (casts + weight transpose + zeroing)
  int prepTotal = N * 32 + 1664 * 128 + 1664 + zwords;
  prep_kernel<<<(prepTotal + 255) / 256, 256, 0, stream>>>(
      x, Wq, Wk, Wv, Wskip, bq, bk, bv, bskip, xb, wcat, bcat, cnt, zwords, N);

  // 2) LDS-free QKV+skip GEMM + slotted edge scatter (no barriers in kernel)
  gemm_mfma_kernel<<<dim3(40, 26), 256, 0, stream>>>(
      xb, wcat, bcat, qb, k8, v8, skip, src, dst, cnt, bsrc, N, E);

  // 3) fused attention (32B/lane gather: half the VMEM instrs) + combine
  attn_combine_kernel<<<(N + 3) / 4, 256, 0, stream>>>(
      qb, k8, v8, cnt, bsrc, skip, Wbeta, out2, colsum, colsq, N);

  // 4) finalize
  int total2 = N * D_DIM / 2;
  final_kernel<<<(total2 + 255) / 256, 256, 0, stream>>>(
      out2, colsum, colsq, gnw, gnb, gnms, x, (float*)d_out, total2, 1.f / (float)N);
}

// Round 6
// 184.860 us; speedup vs baseline: 1.0529x; 1.0529x over previous
//
#include <hip/hip_runtime.h>
#include <hip/hip_bf16.h>
#include <math.h>

// Problem constants: N=10000, E=160000, D=128, H=4, C=128, HC=512
#define D_DIM 128
#define HC_DIM 512
#define CAP 128  // per-node edge bucket capacity (deg ~ Poisson(16); P(deg>=128)<1e-60)
#define REP 4    // colsum/colsq replica slots (per-address atomic depth 2500/REP=625)
#define CHUNK 8  // edges staged to LDS per round

typedef __attribute__((ext_vector_type(8))) short bf16x8;
typedef __attribute__((ext_vector_type(4))) float f32x4;
typedef __attribute__((ext_vector_type(2))) float f32x2;

static __device__ __forceinline__ unsigned short f2bf(float f) {
  unsigned u = __float_as_uint(f);
  unsigned r = (u + 0x7fffu + ((u >> 16) & 1u)) >> 16;  // RNE
  return (unsigned short)r;
}
static __device__ __forceinline__ float bflo(unsigned u) {
  return __uint_as_float(u << 16);
}
static __device__ __forceinline__ float bfhi(unsigned u) {
  return __uint_as_float(u & 0xffff0000u);
}

// async global->LDS: 64 lanes x 16B, per-lane global addr, wave-uniform LDS base
static __device__ __forceinline__ void gload_lds16(const void* g, void* l) {
  __builtin_amdgcn_global_load_lds(
      (const __attribute__((address_space(1))) unsigned int*)g,
      (__attribute__((address_space(3))) unsigned int*)l, 16, 0, 0);
}

// ---------------------------------------------------------------------------
// prep: cast x -> bf16; build Wt [1664][128] bf16 (coalesced source reads);
// bcat[1664]; zero counter region (cnt|colsum|colsq).
// ---------------------------------------------------------------------------
__global__ void prep_kernel(const float* __restrict__ x,
                            const float* __restrict__ Wq, const float* __restrict__ Wk,
                            const float* __restrict__ Wv, const float* __restrict__ Wskip,
                            const float* __restrict__ bq, const float* __restrict__ bk,
                            const float* __restrict__ bv, const float* __restrict__ bskip,
                            unsigned short* __restrict__ xb,
                            unsigned short* __restrict__ wcat,
                            float* __restrict__ bcat,
                            int* __restrict__ zbase, int zwords, int N) {
  int t = blockIdx.x * 256 + threadIdx.x;
  int X4 = N * 32;  // x float4 count
  if (t < X4) {
    float4 f = *(const float4*)&x[t * 4];
    ushort4 o;
    o.x = f2bf(f.x); o.y = f2bf(f.y); o.z = f2bf(f.z); o.w = f2bf(f.w);
    *(ushort4*)&xb[t * 4] = o;
  } else if (t < X4 + 1664 * 128) {
    int widx = t - X4;
    if (widx < 3 * 65536) {
      int segi = widx >> 16;       // 0=q 1=k 2=v
      int r = widx & 65535;
      int kk = r >> 9;             // 0..127
      int m = r & 511;             // consecutive -> coalesced source read
      const float* W = (segi == 0) ? Wq : (segi == 1) ? Wk : Wv;
      wcat[(size_t)(segi * 512 + m) * 128 + kk] = f2bf(W[kk * 512 + m]);
    } else {
      int r = widx - 3 * 65536;    // < 16384
      int kk = r >> 7;
      int m = r & 127;
      wcat[(size_t)(1536 + m) * 128 + kk] = f2bf(Wskip[kk * 128 + m]);
    }
  } else if (t < X4 + 1664 * 128 + 1664) {
    int b = t - X4 - 1664 * 128;
    bcat[b] = (b < 512) ? bq[b] : (b < 1024) ? bk[b - 512]
            : (b < 1536) ? bv[b - 1024] : bskip[b - 1536];
  } else if (t < X4 + 1664 * 128 + 1664 + zwords) {
    zbase[t - X4 - 1664 * 128 - 1664] = 0;
  }
}

// ---------------------------------------------------------------------------
// LDS-free MFMA GEMM + slotted edge scatter (no hist/scan needed).
// [N x 1664] = Xb[N x 128] @ Wt[1664 x 128]^T + bcat.
// cols 0-511 -> q bf16; 512-1023 -> k fp8; 1024-1535 -> v fp8;
// 1536-1663 -> skip fp32.
// ---------------------------------------------------------------------------
__global__ __launch_bounds__(256) void gemm_mfma_kernel(
    const unsigned short* __restrict__ Xb, const unsigned short* __restrict__ Wt,
    const float* __restrict__ bcat, unsigned short* __restrict__ qb,
    unsigned char* __restrict__ k8, unsigned char* __restrict__ v8,
    float* __restrict__ skip,
    const int* __restrict__ src, const int* __restrict__ dst,
    int* __restrict__ cnt, int* __restrict__ bsrc, int N, int E) {
  const int tid = threadIdx.x;
  // --- slotted scatter slice (no barriers anywhere in this kernel) ---
  {
    int nblk = gridDim.x * gridDim.y;
    int lb = blockIdx.y * gridDim.x + blockIdx.x;
    int per = (E + nblk - 1) / nblk;
    int e0 = lb * per;
    int e1 = min(e0 + per, E);
    for (int e = e0 + tid; e < e1; e += 256) {
      int d = dst[e];
      int p = atomicAdd(&cnt[d], 1);
      if (p < CAP) bsrc[d * CAP + p] = src[e];
    }
  }
  // --- GEMM ---
  const int wave = tid >> 6, lane = tid & 63;
  const int l16 = lane & 15, quad = lane >> 4;
  const int row0 = (blockIdx.x * 4 + wave) * 64;  // wave's 64-row slab
  const int col0 = blockIdx.y * 64;               // wave's 64-col slab

  const unsigned short* xrow[4];
#pragma unroll
  for (int i = 0; i < 4; ++i) {
    int r = row0 + i * 16 + l16;
    if (r >= N) r = N - 1;  // clamp; stores masked later
    xrow[i] = Xb + (size_t)r * 128;
  }
  const unsigned short* wrow[4];
  float bias[4];
#pragma unroll
  for (int j = 0; j < 4; ++j) {
    int c = col0 + j * 16 + l16;
    wrow[j] = Wt + (size_t)c * 128;
    bias[j] = bcat[c];
  }

  f32x4 acc[4][4] = {};
#pragma unroll
  for (int kk = 0; kk < 4; ++kk) {
    int k0 = kk * 32 + quad * 8;
    bf16x8 a[4], b[4];
#pragma unroll
    for (int i = 0; i < 4; ++i) a[i] = *(const bf16x8*)(xrow[i] + k0);
#pragma unroll
    for (int j = 0; j < 4; ++j) b[j] = *(const bf16x8*)(wrow[j] + k0);
#pragma unroll
    for (int i = 0; i < 4; ++i)
#pragma unroll
      for (int j = 0; j < 4; ++j)
        acc[i][j] = __builtin_amdgcn_mfma_f32_16x16x32_bf16(a[i], b[j], acc[i][j], 0, 0, 0);
  }

  // wave-uniform output kind: 0=q bf16, 1=k fp8, 2=v fp8, 3=skip fp32
  const int kind = (col0 < 512) ? 0 : (col0 < 1024) ? 1 : (col0 < 1536) ? 2 : 3;
#pragma unroll
  for (int i = 0; i < 4; ++i) {
#pragma unroll
    for (int reg = 0; reg < 4; ++reg) {
      int r = row0 + i * 16 + quad * 4 + reg;
      if (r < N) {
#pragma unroll
        for (int j = 0; j < 4; ++j) {
          int cidx = col0 + j * 16 + l16;
          float val = acc[i][j][reg] + bias[j];
          if (kind == 0) {
            qb[(size_t)r * 512 + cidx] = f2bf(val);
          } else if (kind == 1) {
            int pk = __builtin_amdgcn_cvt_pk_fp8_f32(val, val, 0, false);
            k8[(size_t)r * 512 + cidx - 512] = (unsigned char)pk;
          } else if (kind == 2) {
            int pk = __builtin_amdgcn_cvt_pk_fp8_f32(val, val, 0, false);
            v8[(size_t)r * 512 + cidx - 1024] = (unsigned char)pk;
          } else {
            skip[(size_t)r * 128 + cidx - 1536] = val;
          }
        }
      }
    }
  }
}

// ---------------------------------------------------------------------------
// Fused attention + combine, LDS-STAGED GATHER (global_load_lds).
// Law from R1-R5: dur ~ 1/(resident waves); per-wave VALU duty ~3-4% in
// every register-gather variant (bytes, instr count, structure all null).
// Fix: decouple gather issue from register consumption. Per node, edges
// staged to LDS in chunks of 8: up to 8 global_load_lds_dwordx4 (each
// stages 2 edges' 512B rows: per-lane global addr, wave-uniform LDS dest),
// ONE vmcnt(0) wait per chunk, then all compute runs from LDS. No VGPR
// prefetch buffers -> VGPR stays ~64 (occupancy LDS-capped at 4 blocks/CU,
// 16 waves/CU). Math identical to the round-4 kernel (fp8 k+v, qf[4][8],
// same reductions, beta gate, REP=4 moment atomics).
// ---------------------------------------------------------------------------
__global__ __launch_bounds__(256) void attn_combine_kernel(
    const unsigned short* __restrict__ qb, const unsigned char* __restrict__ k8,
    const unsigned char* __restrict__ v8, const int* __restrict__ cnt,
    const int* __restrict__ bsrc, const float* __restrict__ skip,
    const float* __restrict__ Wbeta, float* __restrict__ out2,
    float* __restrict__ colsum, float* __restrict__ colsq, int N) {
  __shared__ int eL[4][CAP];        // per-wave edge list (wave-local, no sync needed)
  __shared__ float redS[4][128];
  __shared__ float redQ[4][128];
  __shared__ __align__(16) unsigned char kvL[4][2][CHUNK][512];  // [wave][k|v][edge][byte]
  int tid = threadIdx.x;
  int w = tid >> 6, lane = tid & 63;
  int node = blockIdx.x * 4 + w;
  bool nv = node < N;
  int nc = nv ? node : (N - 1);     // clamped for addressing; contributions masked
  int g = lane >> 4, j = lane & 15;

  int count = nv ? min(cnt[nc], CAP) : 0;
  const int* bp = bsrc + (size_t)nc * CAP;
  for (int i = lane; i < count; i += 64) eL[w][i] = bp[i];

  const float qscale = 0.08838834764831845f * 1.4426950408889634f;  // /sqrt(128)*log2e
  // stage q for all 4 heads as scaled f32 (lane j holds dims j*8..j*8+7)
  float qf[4][8];
#pragma unroll
  for (int h = 0; h < 4; ++h) {
    int4 qi = *(const int4*)(qb + (size_t)nc * 512 + h * 128 + j * 8);
    qf[h][0] = bflo(qi.x) * qscale; qf[h][1] = bfhi(qi.x) * qscale;
    qf[h][2] = bflo(qi.y) * qscale; qf[h][3] = bfhi(qi.y) * qscale;
    qf[h][4] = bflo(qi.z) * qscale; qf[h][5] = bfhi(qi.z) * qscale;
    qf[h][6] = bflo(qi.w) * qscale; qf[h][7] = bfhi(qi.w) * qscale;
  }

  float o[4][8];
  float lsum[4];
#pragma unroll
  for (int h = 0; h < 4; ++h) {
    lsum[h] = 0.f;
#pragma unroll
    for (int r = 0; r < 8; ++r) o[h][r] = 0.f;
  }

  if (count > 0) {
    int half = lane >> 5;           // 0: first edge of pair, 1: second
    int b16 = (lane & 31) * 16;     // byte offset within the 512B row
    for (int base = 0; base < count; base += CHUNK) {
      int m = min(CHUNK, count - base);
      // --- stage chunk: ceil(m/2) k-instrs + ceil(m/2) v-instrs ---
      for (int t = 0; 2 * t < m; ++t) {
        int ce = base + 2 * t + half;
        int ei = eL[w][(ce < count) ? ce : (count - 1)];
        const unsigned char* gk = k8 + (size_t)ei * 512 + b16;
        const unsigned char* gv = v8 + (size_t)ei * 512 + b16;
        gload_lds16(gk, &kvL[w][0][2 * t][0]);
        gload_lds16(gv, &kvL[w][1][2 * t][0]);
      }
      asm volatile("s_waitcnt vmcnt(0)" ::: "memory");
      __builtin_amdgcn_sched_barrier(0);
      // --- compute m edges from LDS (groups take chunk-local g, g+4) ---
      for (int s = 0; s < CHUNK && s < m; s += 4) {
        int cl = s + g;
        bool act = cl < m;
        int clc = act ? cl : (m - 1);
        const unsigned char* kp = &kvL[w][0][clc][0];
        const unsigned char* vp = &kvL[w][1][clc][0];
#pragma unroll
        for (int h = 0; h < 4; ++h) {
          uint2 kw = *(const uint2*)(kp + h * 128 + j * 8);
          uint2 vw = *(const uint2*)(vp + h * 128 + j * 8);
          f32x2 k01 = __builtin_amdgcn_cvt_pk_f32_fp8(kw.x, false);
          f32x2 k23 = __builtin_amdgcn_cvt_pk_f32_fp8(kw.x, true);
          f32x2 k45 = __builtin_amdgcn_cvt_pk_f32_fp8(kw.y, false);
          f32x2 k67 = __builtin_amdgcn_cvt_pk_f32_fp8(kw.y, true);
          float p = qf[h][0] * k01.x;
          p = fmaf(qf[h][1], k01.y, p);
          p = fmaf(qf[h][2], k23.x, p);
          p = fmaf(qf[h][3], k23.y, p);
          p = fmaf(qf[h][4], k45.x, p);
          p = fmaf(qf[h][5], k45.y, p);
          p = fmaf(qf[h][6], k67.x, p);
          p = fmaf(qf[h][7], k67.y, p);
          p += __shfl_xor(p, 1);
          p += __shfl_xor(p, 2);
          p += __shfl_xor(p, 4);
          p += __shfl_xor(p, 8);
          float a = act ? p : -1e30f;
          float wgt = exp2f(a);  // exp2(-1e30) = 0 for inactive slots
          f32x2 v01 = __builtin_amdgcn_cvt_pk_f32_fp8(vw.x, false);
          f32x2 v23 = __builtin_amdgcn_cvt_pk_f32_fp8(vw.x, true);
          f32x2 v45 = __builtin_amdgcn_cvt_pk_f32_fp8(vw.y, false);
          f32x2 v67 = __builtin_amdgcn_cvt_pk_f32_fp8(vw.y, true);
          lsum[h] += wgt;
          o[h][0] = fmaf(wgt, v01.x, o[h][0]); o[h][1] = fmaf(wgt, v01.y, o[h][1]);
          o[h][2] = fmaf(wgt, v23.x, o[h][2]); o[h][3] = fmaf(wgt, v23.y, o[h][3]);
          o[h][4] = fmaf(wgt, v45.x, o[h][4]); o[h][5] = fmaf(wgt, v45.y, o[h][5]);
          o[h][6] = fmaf(wgt, v67.x, o[h][6]); o[h][7] = fmaf(wgt, v67.y, o[h][7]);
        }
      }
      // drain LDS reads before next chunk's staging overwrites the buffer
      asm volatile("s_waitcnt lgkmcnt(0)" ::: "memory");
      __builtin_amdgcn_sched_barrier(0);
    }
  }
  // per-head cross-group butterfly + normalize, merged head-mean accumulation
  float am[8];
#pragma unroll
  for (int r = 0; r < 8; ++r) am[r] = 0.f;
#pragma unroll
  for (int h = 0; h < 4; ++h) {
#pragma unroll
    for (int r = 0; r < 8; ++r) {
      o[h][r] += __shfl_xor(o[h][r], 16);
      o[h][r] += __shfl_xor(o[h][r], 32);
    }
    lsum[h] += __shfl_xor(lsum[h], 16);
    lsum[h] += __shfl_xor(lsum[h], 32);
    float inv = 0.25f / (lsum[h] + 1e-16f);   // fold head-mean 1/4 into normalization
#pragma unroll
    for (int r = 0; r < 8; ++r) am[r] += o[h][r] * inv;
  }

  // --- beta gate (per-lane columns j*8..j*8+7, replicated across groups) ---
  float4 sl = *(const float4*)&skip[(size_t)nc * 128 + j * 8];
  float4 sh = *(const float4*)&skip[(size_t)nc * 128 + j * 8 + 4];
  float4 wal = *(const float4*)&Wbeta[j * 8];
  float4 wah = *(const float4*)&Wbeta[j * 8 + 4];
  float4 wbl = *(const float4*)&Wbeta[128 + j * 8];
  float4 wbh = *(const float4*)&Wbeta[128 + j * 8 + 4];
  float4 wcl = *(const float4*)&Wbeta[256 + j * 8];
  float4 wch = *(const float4*)&Wbeta[256 + j * 8 + 4];
  float p = am[0] * wal.x + sl.x * wbl.x + (am[0] - sl.x) * wcl.x
          + am[1] * wal.y + sl.y * wbl.y + (am[1] - sl.y) * wcl.y
          + am[2] * wal.z + sl.z * wbl.z + (am[2] - sl.z) * wcl.z
          + am[3] * wal.w + sl.w * wbl.w + (am[3] - sl.w) * wcl.w
          + am[4] * wah.x + sh.x * wbh.x + (am[4] - sh.x) * wch.x
          + am[5] * wah.y + sh.y * wbh.y + (am[5] - sh.y) * wch.y
          + am[6] * wah.z + sh.z * wbh.z + (am[6] - sh.z) * wch.z
          + am[7] * wah.w + sh.w * wbh.w + (am[7] - sh.w) * wch.w;
  // reduce over 16 j-lanes (each group holds all 128 cols -> full 384-dot)
  p += __shfl_xor(p, 1); p += __shfl_xor(p, 2);
  p += __shfl_xor(p, 4); p += __shfl_xor(p, 8);
  float beta = 1.f / (1.f + __expf(-p));
  float ob = 1.f - beta;
  float vm = nv ? 1.f : 0.f;
  float oc0 = (beta * sl.x + ob * am[0]) * vm;
  float oc1 = (beta * sl.y + ob * am[1]) * vm;
  float oc2 = (beta * sl.z + ob * am[2]) * vm;
  float oc3 = (beta * sl.w + ob * am[3]) * vm;
  float oc4 = (beta * sh.x + ob * am[4]) * vm;
  float oc5 = (beta * sh.y + ob * am[5]) * vm;
  float oc6 = (beta * sh.z + ob * am[6]) * vm;
  float oc7 = (beta * sh.w + ob * am[7]) * vm;

  if (g == 0) {
    float4 lo; lo.x = oc0; lo.y = oc1; lo.z = oc2; lo.w = oc3;
    float4 hi; hi.x = oc4; hi.y = oc5; hi.z = oc6; hi.w = oc7;
    if (nv) {
      *(float4*)&out2[(size_t)node * 128 + j * 8] = lo;
      *(float4*)&out2[(size_t)node * 128 + j * 8 + 4] = hi;
    }
    *(float4*)&redS[w][j * 8] = lo;
    *(float4*)&redS[w][j * 8 + 4] = hi;
    float4 ql; ql.x = oc0 * oc0; ql.y = oc1 * oc1; ql.z = oc2 * oc2; ql.w = oc3 * oc3;
    float4 qh2; qh2.x = oc4 * oc4; qh2.y = oc5 * oc5; qh2.z = oc6 * oc6; qh2.w = oc7 * oc7;
    *(float4*)&redQ[w][j * 8] = ql;
    *(float4*)&redQ[w][j * 8 + 4] = qh2;
  }
  __syncthreads();
  if (w == 0) {
    int c = lane * 2;
    float s0 = redS[0][c] + redS[1][c] + redS[2][c] + redS[3][c];
    float s1 = redS[0][c + 1] + redS[1][c + 1] + redS[2][c + 1] + redS[3][c + 1];
    float q0 = redQ[0][c] + redQ[1][c] + redQ[2][c] + redQ[3][c];
    float q1 = redQ[0][c + 1] + redQ[1][c + 1] + redQ[2][c + 1] + redQ[3][c + 1];
    int slot = (blockIdx.x & (REP - 1)) * 128;
    atomicAdd(&colsum[slot + c], s0);
    atomicAdd(&colsum[slot + c + 1], s1);
    atomicAdd(&colsq[slot + c], q0);
    atomicAdd(&colsq[slot + c + 1], q1);
  }
}

// ---------------------------------------------------------------------------
// finalize: sum REP replica column stats + groupnorm + exact GELU + residual
// ---------------------------------------------------------------------------
__global__ void final_kernel(const float* __restrict__ out2,
                             const float* __restrict__ colsum,
                             const float* __restrict__ colsq,
                             const float* __restrict__ gnw,
                             const float* __restrict__ gnb,
                             const float* __restrict__ gnms,
                             const float* __restrict__ x,
                             float* __restrict__ y, int total2, float invN) {
  int i = blockIdx.x * 256 + threadIdx.x;
  if (i < total2) {
    int c = (i & 63) * 2;
    float2 cs; cs.x = 0.f; cs.y = 0.f;
    float2 cq; cq.x = 0.f; cq.y = 0.f;
#pragma unroll
    for (int s = 0; s < REP; ++s) {
      float2 t = *(const float2*)&colsum[s * 128 + c];
      float2 u = *(const float2*)&colsq[s * 128 + c];
      cs.x += t.x; cs.y += t.y;
      cq.x += u.x; cq.y += u.y;
    }
    float2 gw = *(const float2*)&gnw[c];
    float2 gb = *(const float2*)&gnb[c];
    float2 gs = *(const float2*)&gnms[c];
    float mean0 = cs.x * invN, mean1 = cs.y * invN;
    float var0 = cq.x * invN - mean0 * mean0 * gs.x * (2.f - gs.x);
    float var1 = cq.y * invN - mean1 * mean1 * gs.y * (2.f - gs.y);
    float mul0 = gw.x / sqrtf(var0 + 1e-5f);
    float mul1 = gw.y / sqrtf(var1 + 1e-5f);
    float2 o = *(const float2*)&out2[i * 2];
    float2 xx = *(const float2*)&x[i * 2];
    float t0 = (o.x - gs.x * mean0) * mul0 + gb.x;
    float t1 = (o.y - gs.y * mean1) * mul1 + gb.y;
    float g0 = 0.5f * t0 * (1.f + erff(t0 * 0.70710678118654752f));
    float g1 = 0.5f * t1 * (1.f + erff(t1 * 0.70710678118654752f));
    float2 r; r.x = g0 + xx.x; r.y = g1 + xx.y;
    *(float2*)&y[i * 2] = r;
  }
}

extern "C" void kernel_launch(void* const* d_in, const int* in_sizes, int n_in,
                              void* d_out, int out_size, void* d_ws, size_t ws_size,
                              hipStream_t stream) {
  const float* x     = (const float*)d_in[0];
  const int*   ei    = (const int*)d_in[1];
  const float* Wq    = (const float*)d_in[2];
  const float* bq    = (const float*)d_in[3];
  const float* Wk    = (const float*)d_in[4];
  const float* bk    = (const float*)d_in[5];
  const float* Wv    = (const float*)d_in[6];
  const float* bv    = (const float*)d_in[7];
  const float* Wskip = (const float*)d_in[8];
  const float* bskip = (const float*)d_in[9];
  const float* Wbeta = (const float*)d_in[10];
  const float* gnw   = (const float*)d_in[11];
  const float* gnb   = (const float*)d_in[12];
  const float* gnms  = (const float*)d_in[13];

  const int N = in_sizes[0] / D_DIM;   // 10000
  const int E = in_sizes[1] / 2;       // 160000
  const int* src = ei;
  const int* dst = ei + E;

  // workspace carve-up (alias: xb over out2 — disjoint lifetimes:
  // xb dead after gemm; out2 first written in attn_combine)
  char* p = (char*)d_ws;
  unsigned short* qb = (unsigned short*)p; p += (size_t)N * 512 * 2;      // q bf16
  unsigned char*  k8 = (unsigned char*)p;  p += (size_t)N * 512;          // k fp8
  unsigned char*  v8 = (unsigned char*)p;  p += (size_t)N * 512;          // v fp8
  float*          skip = (float*)p;        p += (size_t)N * 128 * 4;
  float*          out2 = (float*)p;        p += (size_t)N * 128 * 4;
  // contiguous zero region: cnt | colsum[REP][128] | colsq[REP][128]
  int*   cnt    = (int*)p;   p += (size_t)N * 4;
  float* colsum = (float*)p; p += REP * 128 * 4;
  float* colsq  = (float*)p; p += REP * 128 * 4;
  int zwords = N + 2 * REP * 128;
  int* bsrc   = (int*)p;   p += (size_t)N * CAP * 4;  // slotted buckets
  unsigned short* wcat = (unsigned short*)p; p += (size_t)1664 * 128 * 2;
  float* bcat = (float*)p; p += 1664 * 4;
  unsigned short* xb = (unsigned short*)out2;  // alias

  // 1) prep (casts + weight transpose + zeroing)
  int prepTotal = N * 32 + 1664 * 128 + 1664 + zwords;
  prep_kernel<<<(prepTotal + 255) / 256, 256, 0, stream>>>(
      x, Wq, Wk, Wv, Wskip, bq, bk, bv, bskip, xb, wcat, bcat, cnt, zwords, N);

  // 2) LDS-free QKV+skip GEMM + slotted edge scatter (no barriers in kernel)
  gemm_mfma_kernel<<<dim3(40, 26), 256, 0, stream>>>(
      xb, wcat, bcat, qb, k8, v8, skip, src, dst, cnt, bsrc, N, E);

  // 3) fused attention (LDS-staged gather via global_load_lds) + combine
  attn_combine_kernel<<<(N + 3) / 4, 256, 0, stream>>>(
      qb, k8, v8, cnt, bsrc, skip, Wbeta, out2, colsum, colsq, N);

  // 4) finalize
  int total2 = N * D_DIM / 2;
  final_kernel<<<(total2 + 255) / 256, 256, 0, stream>>>(
      out2, colsum, colsq, gnw, gnb, gnms, x, (float*)d_out, total2, 1.f / (float)N);
}

// Round 7
// 179.233 us; speedup vs baseline: 1.0859x; 1.0314x over previous
//
#include <hip/hip_runtime.h>
#include <hip/hip_bf16.h>
#include <math.h>

// Problem constants: N=10000, E=160000, D=128, H=4, C=128, HC=512
#define D_DIM 128
#define HC_DIM 512
#define CAP 128  // per-node edge bucket capacity (deg ~ Poisson(16); P(deg>=128)<1e-60)
#define REP 4    // colsum/colsq replica slots (keeps per-address atomic depth at 2500/REP=625)

typedef __attribute__((ext_vector_type(8))) short bf16x8;
typedef __attribute__((ext_vector_type(4))) float f32x4;
typedef __attribute__((ext_vector_type(2))) float f32x2;
typedef __attribute__((ext_vector_type(2))) _Float16 h16x2;

static __device__ __forceinline__ unsigned short f2bf(float f) {
  unsigned u = __float_as_uint(f);
  unsigned r = (u + 0x7fffu + ((u >> 16) & 1u)) >> 16;  // RNE
  return (unsigned short)r;
}
static __device__ __forceinline__ float bflo(unsigned u) {
  return __uint_as_float(u << 16);
}
static __device__ __forceinline__ float bfhi(unsigned u) {
  return __uint_as_float(u & 0xffff0000u);
}

// ---------------------------------------------------------------------------
// prep: cast x -> bf16; build Wt [1664][128] bf16 (coalesced source reads);
// bcat[1664]; zero counter region (cnt|colsum|colsq).
// ---------------------------------------------------------------------------
__global__ void prep_kernel(const float* __restrict__ x,
                            const float* __restrict__ Wq, const float* __restrict__ Wk,
                            const float* __restrict__ Wv, const float* __restrict__ Wskip,
                            const float* __restrict__ bq, const float* __restrict__ bk,
                            const float* __restrict__ bv, const float* __restrict__ bskip,
                            unsigned short* __restrict__ xb,
                            unsigned short* __restrict__ wcat,
                            float* __restrict__ bcat,
                            int* __restrict__ zbase, int zwords, int N) {
  int t = blockIdx.x * 256 + threadIdx.x;
  int X4 = N * 32;  // x float4 count
  if (t < X4) {
    float4 f = *(const float4*)&x[t * 4];
    ushort4 o;
    o.x = f2bf(f.x); o.y = f2bf(f.y); o.z = f2bf(f.z); o.w = f2bf(f.w);
    *(ushort4*)&xb[t * 4] = o;
  } else if (t < X4 + 1664 * 128) {
    int widx = t - X4;
    if (widx < 3 * 65536) {
      int segi = widx >> 16;       // 0=q 1=k 2=v
      int r = widx & 65535;
      int kk = r >> 9;             // 0..127
      int m = r & 511;             // consecutive -> coalesced source read
      const float* W = (segi == 0) ? Wq : (segi == 1) ? Wk : Wv;
      wcat[(size_t)(segi * 512 + m) * 128 + kk] = f2bf(W[kk * 512 + m]);
    } else {
      int r = widx - 3 * 65536;    // < 16384
      int kk = r >> 7;
      int m = r & 127;
      wcat[(size_t)(1536 + m) * 128 + kk] = f2bf(Wskip[kk * 128 + m]);
    }
  } else if (t < X4 + 1664 * 128 + 1664) {
    int b = t - X4 - 1664 * 128;
    bcat[b] = (b < 512) ? bq[b] : (b < 1024) ? bk[b - 512]
            : (b < 1536) ? bv[b - 1024] : bskip[b - 1536];
  } else if (t < X4 + 1664 * 128 + 1664 + zwords) {
    zbase[t - X4 - 1664 * 128 - 1664] = 0;
  }
}

// ---------------------------------------------------------------------------
// LDS-free MFMA GEMM + slotted edge scatter (no hist/scan needed).
// Safe fusion: no barriers in this kernel -> scatter atomics never gate
// a barrier drain.
// [N x 1664] = Xb[N x 128] @ Wt[1664 x 128]^T + bcat.
// cols 0-511 -> q bf16; 512-1023 -> k f16; 1024-1535 -> v fp8;
// 1536-1663 -> skip fp32.
// ---------------------------------------------------------------------------
__global__ __launch_bounds__(256) void gemm_mfma_kernel(
    const unsigned short* __restrict__ Xb, const unsigned short* __restrict__ Wt,
    const float* __restrict__ bcat, unsigned short* __restrict__ qb,
    unsigned short* __restrict__ kf, unsigned char* __restrict__ v8,
    float* __restrict__ skip,
    const int* __restrict__ src, const int* __restrict__ dst,
    int* __restrict__ cnt, int* __restrict__ bsrc, int N, int E) {
  const int tid = threadIdx.x;
  // --- slotted scatter slice (no barriers anywhere in this kernel) ---
  {
    int nblk = gridDim.x * gridDim.y;
    int lb = blockIdx.y * gridDim.x + blockIdx.x;
    int per = (E + nblk - 1) / nblk;
    int e0 = lb * per;
    int e1 = min(e0 + per, E);
    for (int e = e0 + tid; e < e1; e += 256) {
      int d = dst[e];
      int p = atomicAdd(&cnt[d], 1);
      if (p < CAP) bsrc[d * CAP + p] = src[e];
    }
  }
  // --- GEMM ---
  const int wave = tid >> 6, lane = tid & 63;
  const int l16 = lane & 15, quad = lane >> 4;
  const int row0 = (blockIdx.x * 4 + wave) * 64;  // wave's 64-row slab
  const int col0 = blockIdx.y * 64;               // wave's 64-col slab

  const unsigned short* xrow[4];
#pragma unroll
  for (int i = 0; i < 4; ++i) {
    int r = row0 + i * 16 + l16;
    if (r >= N) r = N - 1;  // clamp; stores masked later
    xrow[i] = Xb + (size_t)r * 128;
  }
  const unsigned short* wrow[4];
  float bias[4];
#pragma unroll
  for (int j = 0; j < 4; ++j) {
    int c = col0 + j * 16 + l16;
    wrow[j] = Wt + (size_t)c * 128;
    bias[j] = bcat[c];
  }

  f32x4 acc[4][4] = {};
#pragma unroll
  for (int kk = 0; kk < 4; ++kk) {
    int k0 = kk * 32 + quad * 8;
    bf16x8 a[4], b[4];
#pragma unroll
    for (int i = 0; i < 4; ++i) a[i] = *(const bf16x8*)(xrow[i] + k0);
#pragma unroll
    for (int j = 0; j < 4; ++j) b[j] = *(const bf16x8*)(wrow[j] + k0);
#pragma unroll
    for (int i = 0; i < 4; ++i)
#pragma unroll
      for (int j = 0; j < 4; ++j)
        acc[i][j] = __builtin_amdgcn_mfma_f32_16x16x32_bf16(a[i], b[j], acc[i][j], 0, 0, 0);
  }

  // wave-uniform output kind: 0=q bf16, 1=k f16, 2=v fp8, 3=skip fp32
  const int kind = (col0 < 512) ? 0 : (col0 < 1024) ? 1 : (col0 < 1536) ? 2 : 3;
#pragma unroll
  for (int i = 0; i < 4; ++i) {
#pragma unroll
    for (int reg = 0; reg < 4; ++reg) {
      int r = row0 + i * 16 + quad * 4 + reg;
      if (r < N) {
#pragma unroll
        for (int j = 0; j < 4; ++j) {
          int cidx = col0 + j * 16 + l16;
          float val = acc[i][j][reg] + bias[j];
          if (kind == 0) {
            qb[(size_t)r * 512 + cidx] = f2bf(val);
          } else if (kind == 1) {
            _Float16 hv = (_Float16)val;
            kf[(size_t)r * 512 + cidx - 512] = *(unsigned short*)&hv;
          } else if (kind == 2) {
            int pk = __builtin_amdgcn_cvt_pk_fp8_f32(val, val, 0, false);
            v8[(size_t)r * 512 + cidx - 1024] = (unsigned char)pk;
          } else {
            skip[(size_t)r * 128 + cidx - 1536] = val;
          }
        }
      }
    }
  }
}

// ---------------------------------------------------------------------------
// Fused attention + combine, ALL 4 HEADS IN ONE EDGE LOOP.
// REVERT TO ROUND-2 (session best: attn 52.2 us, total 178.9).
// Cross-round evidence: attn duration invariant to gathered bytes (-37%),
// VMEM instr count (-50%), parallelism (x4), and staging mechanism
// (global_load_lds); strictly worse when VGPR > 64. This configuration is
// the measured optimum of that family.
// Block = 4 nodes (wave = node); each 16-lane group owns one edge slot and
// computes all 4 heads for that edge. Edge list staged in LDS; depth-1 k/v
// prefetch. Beta gate + out2 + column moments in-block (REP=4 atomics).
// ---------------------------------------------------------------------------
__global__ __launch_bounds__(256) void attn_combine_kernel(
    const unsigned short* __restrict__ qb, const unsigned short* __restrict__ kf,
    const unsigned char* __restrict__ v8, const int* __restrict__ cnt,
    const int* __restrict__ bsrc, const float* __restrict__ skip,
    const float* __restrict__ Wbeta, float* __restrict__ out2,
    float* __restrict__ colsum, float* __restrict__ colsq, int N) {
  __shared__ int eL[4][CAP];        // per-wave edge list (wave-local, no sync needed)
  __shared__ float redS[4][128];
  __shared__ float redQ[4][128];
  int tid = threadIdx.x;
  int w = tid >> 6, lane = tid & 63;
  int node = blockIdx.x * 4 + w;
  bool nv = node < N;
  int nc = nv ? node : (N - 1);     // clamped for addressing; contributions masked
  int g = lane >> 4, j = lane & 15;

  int count = nv ? min(cnt[nc], CAP) : 0;
  const int* bp = bsrc + (size_t)nc * CAP;
  for (int i = lane; i < count; i += 64) eL[w][i] = bp[i];

  const float qscale = 0.08838834764831845f * 1.4426950408889634f;  // /sqrt(128)*log2e
  // stage q for all 4 heads (lane j holds halves j*8..j*8+7 of each head slice)
  h16x2 qh[4][4];
#pragma unroll
  for (int h = 0; h < 4; ++h) {
    int4 qi = *(const int4*)(qb + (size_t)nc * 512 + h * 128 + j * 8);
    qh[h][0][0] = (_Float16)(bflo(qi.x) * qscale); qh[h][0][1] = (_Float16)(bfhi(qi.x) * qscale);
    qh[h][1][0] = (_Float16)(bflo(qi.y) * qscale); qh[h][1][1] = (_Float16)(bfhi(qi.y) * qscale);
    qh[h][2][0] = (_Float16)(bflo(qi.z) * qscale); qh[h][2][1] = (_Float16)(bfhi(qi.z) * qscale);
    qh[h][3][0] = (_Float16)(bflo(qi.w) * qscale); qh[h][3][1] = (_Float16)(bfhi(qi.w) * qscale);
  }

  float o[4][8];
  float lsum[4];
#pragma unroll
  for (int h = 0; h < 4; ++h) {
    lsum[h] = 0.f;
#pragma unroll
    for (int r = 0; r < 8; ++r) o[h][r] = 0.f;
  }

  if (count > 0) {
    // prologue prefetch (edge index from LDS; k/v for all 4 heads)
    int e = eL[w][(g < count) ? g : 0];
    uint4 kw[4]; uint2 vw[4];
    {
      const unsigned short* kbe = kf + (size_t)e * 512 + j * 8;
      const unsigned char* vbe = v8 + (size_t)e * 512 + j * 8;
#pragma unroll
      for (int h = 0; h < 4; ++h) {
        kw[h] = *(const uint4*)(kbe + h * 128);
        vw[h] = *(const uint2*)(vbe + h * 128);
      }
    }
    for (int idx = 0; idx < count; idx += 4) {
      int rem = count - idx;
      int nrem = rem - 4;
      int en = (nrem > 0) ? eL[w][idx + 4 + ((g < nrem) ? g : 0)] : e;
      uint4 kwn[4]; uint2 vwn[4];
      {
        const unsigned short* kbe = kf + (size_t)en * 512 + j * 8;
        const unsigned char* vbe = v8 + (size_t)en * 512 + j * 8;
#pragma unroll
        for (int h = 0; h < 4; ++h) {
          kwn[h] = *(const uint4*)(kbe + h * 128);
          vwn[h] = *(const uint2*)(vbe + h * 128);
        }
      }
      bool act = (g < rem);
#pragma unroll
      for (int h = 0; h < 4; ++h) {
        float p = __builtin_amdgcn_fdot2(qh[h][0], *(h16x2*)&kw[h].x, 0.f, false);
        p = __builtin_amdgcn_fdot2(qh[h][1], *(h16x2*)&kw[h].y, p, false);
        p = __builtin_amdgcn_fdot2(qh[h][2], *(h16x2*)&kw[h].z, p, false);
        p = __builtin_amdgcn_fdot2(qh[h][3], *(h16x2*)&kw[h].w, p, false);
        p += __shfl_xor(p, 1);
        p += __shfl_xor(p, 2);
        p += __shfl_xor(p, 4);
        p += __shfl_xor(p, 8);
        float a = act ? p : -1e30f;
        float wgt = exp2f(a);  // exp2(-1e30) = 0 for inactive slots
        f32x2 v01 = __builtin_amdgcn_cvt_pk_f32_fp8(vw[h].x, false);
        f32x2 v23 = __builtin_amdgcn_cvt_pk_f32_fp8(vw[h].x, true);
        f32x2 v45 = __builtin_amdgcn_cvt_pk_f32_fp8(vw[h].y, false);
        f32x2 v67 = __builtin_amdgcn_cvt_pk_f32_fp8(vw[h].y, true);
        lsum[h] += wgt;
        o[h][0] += wgt * v01.x; o[h][1] += wgt * v01.y;
        o[h][2] += wgt * v23.x; o[h][3] += wgt * v23.y;
        o[h][4] += wgt * v45.x; o[h][5] += wgt * v45.y;
        o[h][6] += wgt * v67.x; o[h][7] += wgt * v67.y;
        // rotate this head's buffers
        kw[h] = kwn[h]; vw[h] = vwn[h];
      }
      e = en;
    }
  }
  // per-head cross-group butterfly + normalize, merged head-mean accumulation
  float am[8];
#pragma unroll
  for (int r = 0; r < 8; ++r) am[r] = 0.f;
#pragma unroll
  for (int h = 0; h < 4; ++h) {
#pragma unroll
    for (int r = 0; r < 8; ++r) {
      o[h][r] += __shfl_xor(o[h][r], 16);
      o[h][r] += __shfl_xor(o[h][r], 32);
    }
    lsum[h] += __shfl_xor(lsum[h], 16);
    lsum[h] += __shfl_xor(lsum[h], 32);
    float inv = 0.25f / (lsum[h] + 1e-16f);   // fold head-mean 1/4 into normalization
#pragma unroll
    for (int r = 0; r < 8; ++r) am[r] += o[h][r] * inv;
  }

  // --- beta gate (per-lane columns j*8..j*8+7, replicated across groups) ---
  float4 sl = *(const float4*)&skip[(size_t)nc * 128 + j * 8];
  float4 sh = *(const float4*)&skip[(size_t)nc * 128 + j * 8 + 4];
  float4 wal = *(const float4*)&Wbeta[j * 8];
  float4 wah = *(const float4*)&Wbeta[j * 8 + 4];
  float4 wbl = *(const float4*)&Wbeta[128 + j * 8];
  float4 wbh = *(const float4*)&Wbeta[128 + j * 8 + 4];
  float4 wcl = *(const float4*)&Wbeta[256 + j * 8];
  float4 wch = *(const float4*)&Wbeta[256 + j * 8 + 4];
  float p = am[0] * wal.x + sl.x * wbl.x + (am[0] - sl.x) * wcl.x
          + am[1] * wal.y + sl.y * wbl.y + (am[1] - sl.y) * wcl.y
          + am[2] * wal.z + sl.z * wbl.z + (am[2] - sl.z) * wcl.z
          + am[3] * wal.w + sl.w * wbl.w + (am[3] - sl.w) * wcl.w
          + am[4] * wah.x + sh.x * wbh.x + (am[4] - sh.x) * wch.x
          + am[5] * wah.y + sh.y * wbh.y + (am[5] - sh.y) * wch.y
          + am[6] * wah.z + sh.z * wbh.z + (am[6] - sh.z) * wch.z
          + am[7] * wah.w + sh.w * wbh.w + (am[7] - sh.w) * wch.w;
  // reduce over 16 j-lanes (each group holds all 128 cols -> full 384-dot)
  p += __shfl_xor(p, 1); p += __shfl_xor(p, 2);
  p += __shfl_xor(p, 4); p += __shfl_xor(p, 8);
  float beta = 1.f / (1.f + __expf(-p));
  float ob = 1.f - beta;
  float vm = nv ? 1.f : 0.f;
  float oc0 = (beta * sl.x + ob * am[0]) * vm;
  float oc1 = (beta * sl.y + ob * am[1]) * vm;
  float oc2 = (beta * sl.z + ob * am[2]) * vm;
  float oc3 = (beta * sl.w + ob * am[3]) * vm;
  float oc4 = (beta * sh.x + ob * am[4]) * vm;
  float oc5 = (beta * sh.y + ob * am[5]) * vm;
  float oc6 = (beta * sh.z + ob * am[6]) * vm;
  float oc7 = (beta * sh.w + ob * am[7]) * vm;

  if (g == 0) {
    float4 lo; lo.x = oc0; lo.y = oc1; lo.z = oc2; lo.w = oc3;
    float4 hi; hi.x = oc4; hi.y = oc5; hi.z = oc6; hi.w = oc7;
    if (nv) {
      *(float4*)&out2[(size_t)node * 128 + j * 8] = lo;
      *(float4*)&out2[(size_t)node * 128 + j * 8 + 4] = hi;
    }
    *(float4*)&redS[w][j * 8] = lo;
    *(float4*)&redS[w][j * 8 + 4] = hi;
    float4 ql; ql.x = oc0 * oc0; ql.y = oc1 * oc1; ql.z = oc2 * oc2; ql.w = oc3 * oc3;
    float4 qh2; qh2.x = oc4 * oc4; qh2.y = oc5 * oc5; qh2.z = oc6 * oc6; qh2.w = oc7 * oc7;
    *(float4*)&redQ[w][j * 8] = ql;
    *(float4*)&redQ[w][j * 8 + 4] = qh2;
  }
  __syncthreads();
  if (w == 0) {
    int c = lane * 2;
    float s0 = redS[0][c] + redS[1][c] + redS[2][c] + redS[3][c];
    float s1 = redS[0][c + 1] + redS[1][c + 1] + redS[2][c + 1] + redS[3][c + 1];
    float q0 = redQ[0][c] + redQ[1][c] + redQ[2][c] + redQ[3][c];
    float q1 = redQ[0][c + 1] + redQ[1][c + 1] + redQ[2][c + 1] + redQ[3][c + 1];
    int slot = (blockIdx.x & (REP - 1)) * 128;
    atomicAdd(&colsum[slot + c], s0);
    atomicAdd(&colsum[slot + c + 1], s1);
    atomicAdd(&colsq[slot + c], q0);
    atomicAdd(&colsq[slot + c + 1], q1);
  }
}

// ---------------------------------------------------------------------------
// finalize: sum REP replica column stats + groupnorm + exact GELU + residual
// ---------------------------------------------------------------------------
__global__ void final_kernel(const float* __restrict__ out2,
                             const float* __restrict__ colsum,
                             const float* __restrict__ colsq,
                             const float* __restrict__ gnw,
                             const float* __restrict__ gnb,
                             const float* __restrict__ gnms,
                             const float* __restrict__ x,
                             float* __restrict__ y, int total2, float invN) {
  int i = blockIdx.x * 256 + threadIdx.x;
  if (i < total2) {
    int c = (i & 63) * 2;
    float2 cs; cs.x = 0.f; cs.y = 0.f;
    float2 cq; cq.x = 0.f; cq.y = 0.f;
#pragma unroll
    for (int s = 0; s < REP; ++s) {
      float2 t = *(const float2*)&colsum[s * 128 + c];
      float2 u = *(const float2*)&colsq[s * 128 + c];
      cs.x += t.x; cs.y += t.y;
      cq.x += u.x; cq.y += u.y;
    }
    float2 gw = *(const float2*)&gnw[c];
    float2 gb = *(const float2*)&gnb[c];
    float2 gs = *(const float2*)&gnms[c];
    float mean0 = cs.x * invN, mean1 = cs.y * invN;
    float var0 = cq.x * invN - mean0 * mean0 * gs.x * (2.f - gs.x);
    float var1 = cq.y * invN - mean1 * mean1 * gs.y * (2.f - gs.y);
    float mul0 = gw.x / sqrtf(var0 + 1e-5f);
    float mul1 = gw.y / sqrtf(var1 + 1e-5f);
    float2 o = *(const float2*)&out2[i * 2];
    float2 xx = *(const float2*)&x[i * 2];
    float t0 = (o.x - gs.x * mean0) * mul0 + gb.x;
    float t1 = (o.y - gs.y * mean1) * mul1 + gb.y;
    float g0 = 0.5f * t0 * (1.f + erff(t0 * 0.70710678118654752f));
    float g1 = 0.5f * t1 * (1.f + erff(t1 * 0.70710678118654752f));
    float2 r; r.x = g0 + xx.x; r.y = g1 + xx.y;
    *(float2*)&y[i * 2] = r;
  }
}

extern "C" void kernel_launch(void* const* d_in, const int* in_sizes, int n_in,
                              void* d_out, int out_size, void* d_ws, size_t ws_size,
                              hipStream_t stream) {
  const float* x     = (const float*)d_in[0];
  const int*   ei    = (const int*)d_in[1];
  const float* Wq    = (const float*)d_in[2];
  const float* bq    = (const float*)d_in[3];
  const float* Wk    = (const float*)d_in[4];
  const float* bk    = (const float*)d_in[5];
  const float* Wv    = (const float*)d_in[6];
  const float* bv    = (const float*)d_in[7];
  const float* Wskip = (const float*)d_in[8];
  const float* bskip = (const float*)d_in[9];
  const float* Wbeta = (const float*)d_in[10];
  const float* gnw   = (const float*)d_in[11];
  const float* gnb   = (const float*)d_in[12];
  const float* gnms  = (const float*)d_in[13];

  const int N = in_sizes[0] / D_DIM;   // 10000
  const int E = in_sizes[1] / 2;       // 160000
  const int* src = ei;
  const int* dst = ei + E;

  // workspace carve-up (alias: xb over out2 — disjoint lifetimes:
  // xb dead after gemm; out2 first written in attn_combine)
  char* p = (char*)d_ws;
  unsigned short* qb = (unsigned short*)p; p += (size_t)N * 512 * 2;      // q bf16
  unsigned short* kf = (unsigned short*)p; p += (size_t)N * 512 * 2;      // k f16
  unsigned char*  v8 = (unsigned char*)p;  p += (size_t)N * 512;          // v fp8
  float*          skip = (float*)p;        p += (size_t)N * 128 * 4;
  float*          out2 = (float*)p;        p += (size_t)N * 128 * 4;
  // contiguous zero region: cnt | colsum[REP][128] | colsq[REP][128]
  int*   cnt    = (int*)p;   p += (size_t)N * 4;
  float* colsum = (float*)p; p += REP * 128 * 4;
  float* colsq  = (float*)p; p += REP * 128 * 4;
  int zwords = N + 2 * REP * 128;
  int* bsrc   = (int*)p;   p += (size_t)N * CAP * 4;  // slotted buckets
  unsigned short* wcat = (unsigned short*)p; p += (size_t)1664 * 128 * 2;
  float* bcat = (float*)p; p += 1664 * 4;
  unsigned short* xb = (unsigned short*)out2;  // alias

  // 1) prep (casts + weight transpose + zeroing)
  int prepTotal = N * 32 + 1664 * 128 + 1664 + zwords;
  prep_kernel<<<(prepTotal + 255) / 256, 256, 0, stream>>>(
      x, Wq, Wk, Wv, Wskip, bq, bk, bv, bskip, xb, wcat, bcat, cnt, zwords, N);

  // 2) LDS-free QKV+skip GEMM + slotted edge scatter (no barriers in kernel)
  gemm_mfma_kernel<<<dim3(40, 26), 256, 0, stream>>>(
      xb, wcat, bcat, qb, kf, v8, skip, src, dst, cnt, bsrc, N, E);

  // 3) fused attention (all heads per edge) + beta gate + column moments
  attn_combine_kernel<<<(N + 3) / 4, 256, 0, stream>>>(
      qb, kf, v8, cnt, bsrc, skip, Wbeta, out2, colsum, colsq, N);

  // 4) finalize
  int total2 = N * D_DIM / 2;
  final_kernel<<<(total2 + 255) / 256, 256, 0, stream>>>(
      out2, colsum, colsq, gnw, gnb, gnms, x, (float*)d_out, total2, 1.f / (float)N);
}